// Round 2
// baseline (517.059 us; speedup 1.0000x reference)
//
#include <hip/hip_runtime.h>

namespace {

constexpr int Sn = 256;   // encoder sequence length
constexpr int Tn = 12;    // decoder length
constexpr float L2E = 1.44269504088896340736f;  // log2(e)

typedef float v2f __attribute__((ext_vector_type(2)));

__device__ __forceinline__ v2f pkfma(v2f a, v2f b, v2f c) {
  return __builtin_elementwise_fma(a, b, c);  // -> v_pk_fma_f32 on gfx950
}

__device__ __forceinline__ float rcp_(float x) { return __builtin_amdgcn_rcpf(x); }

// Direct 2^x. Gate pre-activations are pre-scaled by +/-log2e at weight-load
// time, so activations need no runtime log2e multiply.
#if __has_builtin(__builtin_amdgcn_exp2f)
__device__ __forceinline__ float exp2_(float x) { return __builtin_amdgcn_exp2f(x); }
#else
// __expf(y) = exp2(y*log2e); feed y = x*ln2 so the net is exp2(x). One extra
// mul vs the builtin, still correct.
__device__ __forceinline__ float exp2_(float x) { return __expf(x * 0.69314718055994530942f); }
#endif

// quad_perm DPP: lane i reads lane sel_i of its 4-lane quad. VALU-rate cross-lane.
template <int CTRL>
__device__ __forceinline__ float qperm(float v) {
  return __int_as_float(
      __builtin_amdgcn_mov_dpp(__float_as_int(v), CTRL, 0xF, 0xF, true));
}
constexpr int DPP_XOR1 = 0xB1;  // [1,0,3,2]
constexpr int DPP_XOR2 = 0x4E;  // [2,3,0,1]
constexpr int DPP_XOR3 = 0x1B;  // [3,2,1,0]
constexpr int DPP_BC0 = 0x00;   // [0,0,0,0]

// Pre-scaled gates: g01 = (-L2E*i, -L2E*f), g23 = (2*L2E*g, -L2E*o).
// sigm(z) = rcp(1 + 2^(-L2E*z)) ; tanh(z) = 1 - 2*rcp(2^(2*L2E*z) + 1).
// Saturation: 2^inf -> inf -> rcp -> 0 ; 2^-inf -> 0. No NaNs.
__device__ __forceinline__ float unit_update(v2f g01, v2f g23, float& c) {
  float iv = rcp_(1.0f + exp2_(g01.x));
  float fv = rcp_(1.0f + exp2_(g01.y));
  float gv = fmaf(-2.0f, rcp_(exp2_(g23.x) + 1.0f), 1.0f);
  float ov = rcp_(1.0f + exp2_(g23.y));
  c = fmaf(fv, c, iv * gv);
  float th = fmaf(-2.0f, rcp_(exp2_(c * (2.0f * L2E)) + 1.0f), 1.0f);
  return ov * th;
}

__device__ __forceinline__ void quad_gather(float h, float* hg) {
  hg[0] = h;
  hg[1] = qperm<DPP_XOR1>(h);
  hg[2] = qperm<DPP_XOR2>(h);
  hg[3] = qperm<DPP_XOR3>(h);
}

// __launch_bounds__(64, 2): grid provides exactly 2 waves/SIMD; cap VGPR at 256
// so the larger live set (raw x buffer + xc ping-pong) can't drop us to 1.
__global__ __launch_bounds__(64, 2) void seq2seq_kernel(
    const float* __restrict__ src, const float* __restrict__ trg,
    const float* __restrict__ eWih0, const float* __restrict__ eWhh0,
    const float* __restrict__ ebih0, const float* __restrict__ ebhh0,
    const float* __restrict__ eWih1, const float* __restrict__ eWhh1,
    const float* __restrict__ ebih1, const float* __restrict__ ebhh1,
    const float* __restrict__ dWih0, const float* __restrict__ dWhh0,
    const float* __restrict__ dbih0, const float* __restrict__ dbhh0,
    const float* __restrict__ dWih1, const float* __restrict__ dWhh1,
    const float* __restrict__ dbih1, const float* __restrict__ dbhh1,
    const float* __restrict__ fcW, const float* __restrict__ fcb,
    float* __restrict__ out) {
  const int gid = blockIdx.x * 64 + threadIdx.x;
  const int e = gid >> 2;  // batch element
  const int u = gid & 3;   // hidden unit owned by this lane

  // Gate rows for this lane: i=u, f=4+u, g=8+u, o=12+u.
  const int ri = u, rf = 4 + u, rg = 8 + u, ro = 12 + u;

  // Activation scale folded into weights: (i,f) and o get -L2E (sigmoid),
  // g gets +2*L2E (tanh).
  const v2f s01 = v2f{-L2E, -L2E};
  const v2f s23 = v2f{2.0f * L2E, -L2E};

  v2f w0x01[8], w0x23[8], w0h01[4], w0h23[4];
  v2f w1i01[4], w1i23[4], w1h01[4], w1h23[4];
#pragma unroll
  for (int j = 0; j < 8; ++j) {
    w0x01[j] = v2f{eWih0[ri * 8 + j], eWih0[rf * 8 + j]} * s01;
    w0x23[j] = v2f{eWih0[rg * 8 + j], eWih0[ro * 8 + j]} * s23;
  }
#pragma unroll
  for (int k = 0; k < 4; ++k) {
    const int kc = u ^ k;
    w0h01[k] = v2f{eWhh0[ri * 4 + kc], eWhh0[rf * 4 + kc]} * s01;
    w0h23[k] = v2f{eWhh0[rg * 4 + kc], eWhh0[ro * 4 + kc]} * s23;
    w1i01[k] = v2f{eWih1[ri * 4 + kc], eWih1[rf * 4 + kc]} * s01;
    w1i23[k] = v2f{eWih1[rg * 4 + kc], eWih1[ro * 4 + kc]} * s23;
    w1h01[k] = v2f{eWhh1[ri * 4 + kc], eWhh1[rf * 4 + kc]} * s01;
    w1h23[k] = v2f{eWhh1[rg * 4 + kc], eWhh1[ro * 4 + kc]} * s23;
  }
  const v2f b0_01 = v2f{ebih0[ri] + ebhh0[ri], ebih0[rf] + ebhh0[rf]} * s01;
  const v2f b0_23 = v2f{ebih0[rg] + ebhh0[rg], ebih0[ro] + ebhh0[ro]} * s23;
  const v2f b1_01 = v2f{ebih1[ri] + ebhh1[ri], ebih1[rf] + ebhh1[rf]} * s01;
  const v2f b1_23 = v2f{ebih1[rg] + ebhh1[rg], ebih1[ro] + ebhh1[ro]} * s23;

  const float4* sp = (const float4*)(src + (size_t)e * (Sn * 8));

  float h0g[4] = {0, 0, 0, 0};  // h0g[k] = h0[u^k]
  float h1g[4] = {0, 0, 0, 0};
  float c0 = 0.0f, c1 = 0.0f;

  // xc = W0x·x + b0 (pre-scaled): the recurrence-independent part of layer 0,
  // computed out-of-band as bubble-filler. Ping-pong A/B (8 steps each).
  v2f xA01[8], xA23[8], xB01[8], xB23[8];
  float4 raw[16];  // raw x for one 8-step block, loaded ~4 steps before convert

  // Convert raw steps r into (o01, o23).
  auto convert = [&](int r, v2f& o01, v2f& o23) {
    float4 xa = raw[2 * r], xb = raw[2 * r + 1];
    float x[8] = {xa.x, xa.y, xa.z, xa.w, xb.x, xb.y, xb.z, xb.w};
    v2f a01 = b0_01, a23 = b0_23;
#pragma unroll
    for (int j = 0; j < 8; ++j) {
      v2f xx = v2f{x[j], x[j]};
      a01 = pkfma(xx, w0x01[j], a01);
      a23 = pkfma(xx, w0x23[j], a23);
    }
    o01 = a01;
    o23 = a23;
  };

  // One recurrent step given the precomputed x-contribution.
  // Layer-1 accumulates its h1-dependent half BEFORE the h0-dependent half so
  // only 4 pkfma sit on the critical path after h0 resolves.
  auto rstep = [&](v2f a01, v2f a23) {
#pragma unroll
    for (int k = 0; k < 4; ++k) {
      v2f hh = v2f{h0g[k], h0g[k]};
      a01 = pkfma(hh, w0h01[k], a01);
      a23 = pkfma(hh, w0h23[k], a23);
    }
    float h0 = unit_update(a01, a23, c0);
    quad_gather(h0, h0g);

    v2f e01 = b1_01, e23 = b1_23;
#pragma unroll
    for (int k = 0; k < 4; ++k) {  // h1 part first (independent of h0)
      v2f hh = v2f{h1g[k], h1g[k]};
      e01 = pkfma(hh, w1h01[k], e01);
      e23 = pkfma(hh, w1h23[k], e23);
    }
#pragma unroll
    for (int k = 0; k < 4; ++k) {  // h0 part last (short tail on critical path)
      v2f hh = v2f{h0g[k], h0g[k]};
      e01 = pkfma(hh, w1i01[k], e01);
      e23 = pkfma(hh, w1i23[k], e23);
    }
    float h1 = unit_update(e01, e23, c1);
    quad_gather(h1, h1g);
  };

  // ---------------- encoder: 256 steps = 32 blocks of 8 ----------------
  // Prologue: block 0 -> A (blocking), then issue loads for block 1.
#pragma unroll
  for (int j = 0; j < 16; ++j) raw[j] = sp[j];
#pragma unroll
  for (int r = 0; r < 8; ++r) convert(r, xA01[r], xA23[r]);
#pragma unroll
  for (int j = 0; j < 16; ++j) raw[j] = sp[16 + j];

  for (int i = 0; i < 16; ++i) {
    // ---- block 2i from A; convert raw (block 2i+1) -> B during steps 4..7 --
    rstep(xA01[0], xA23[0]);
    rstep(xA01[1], xA23[1]);
    rstep(xA01[2], xA23[2]);
    rstep(xA01[3], xA23[3]);
    rstep(xA01[4], xA23[4]); convert(0, xB01[0], xB23[0]); convert(1, xB01[1], xB23[1]);
    rstep(xA01[5], xA23[5]); convert(2, xB01[2], xB23[2]); convert(3, xB01[3], xB23[3]);
    rstep(xA01[6], xA23[6]); convert(4, xB01[4], xB23[4]); convert(5, xB01[5], xB23[5]);
    rstep(xA01[7], xA23[7]); convert(6, xB01[6], xB23[6]); convert(7, xB01[7], xB23[7]);
    if (i < 15) {  // issue loads for block 2i+2 (consumed 4+ steps from now)
#pragma unroll
      for (int j = 0; j < 16; ++j) raw[j] = sp[32 * (i + 1) + j];
    }
    // ---- block 2i+1 from B; convert raw (block 2i+2) -> A during steps 4..7
    rstep(xB01[0], xB23[0]);
    rstep(xB01[1], xB23[1]);
    rstep(xB01[2], xB23[2]);
    rstep(xB01[3], xB23[3]);
    if (i < 15) {
      rstep(xB01[4], xB23[4]); convert(0, xA01[0], xA23[0]); convert(1, xA01[1], xA23[1]);
      rstep(xB01[5], xB23[5]); convert(2, xA01[2], xA23[2]); convert(3, xA01[3], xA23[3]);
      rstep(xB01[6], xB23[6]); convert(4, xA01[4], xA23[4]); convert(5, xA01[5], xA23[5]);
      rstep(xB01[7], xB23[7]); convert(6, xA01[6], xA23[6]); convert(7, xA01[7], xA23[7]);
      // issue loads for block 2i+3
#pragma unroll
      for (int j = 0; j < 16; ++j) raw[j] = sp[32 * (i + 1) + 16 + j];
    } else {
      rstep(xB01[4], xB23[4]);
      rstep(xB01[5], xB23[5]);
      rstep(xB01[6], xB23[6]);
      rstep(xB01[7], xB23[7]);
    }
  }

  // ---- decoder weights (loaded after encoder; encoder weights now dead) ----
  v2f dw0i01 = v2f{dWih0[ri], dWih0[rf]} * s01;
  v2f dw0i23 = v2f{dWih0[rg], dWih0[ro]} * s23;
  v2f dw0h01[4], dw0h23[4], dw1i01[4], dw1i23[4], dw1h01[4], dw1h23[4];
#pragma unroll
  for (int k = 0; k < 4; ++k) {
    const int kc = u ^ k;
    dw0h01[k] = v2f{dWhh0[ri * 4 + kc], dWhh0[rf * 4 + kc]} * s01;
    dw0h23[k] = v2f{dWhh0[rg * 4 + kc], dWhh0[ro * 4 + kc]} * s23;
    dw1i01[k] = v2f{dWih1[ri * 4 + kc], dWih1[rf * 4 + kc]} * s01;
    dw1i23[k] = v2f{dWih1[rg * 4 + kc], dWih1[ro * 4 + kc]} * s23;
    dw1h01[k] = v2f{dWhh1[ri * 4 + kc], dWhh1[rf * 4 + kc]} * s01;
    dw1h23[k] = v2f{dWhh1[rg * 4 + kc], dWhh1[ro * 4 + kc]} * s23;
  }
  const v2f db0_01 = v2f{dbih0[ri] + dbhh0[ri], dbih0[rf] + dbhh0[rf]} * s01;
  const v2f db0_23 = v2f{dbih0[rg] + dbhh0[rg], dbih0[ro] + dbhh0[ro]} * s23;
  const v2f db1_01 = v2f{dbih1[ri] + dbhh1[ri], dbih1[rf] + dbhh1[rf]} * s01;
  const v2f db1_23 = v2f{dbih1[rg] + dbhh1[rg], dbih1[ro] + dbhh1[ro]} * s23;
  float fcw[4];
#pragma unroll
  for (int k = 0; k < 4; ++k) fcw[k] = fcW[u ^ k];
  const float fcbv = fcb[0];

  // ---------------- decoder: 11 steps ----------------
  float xv = trg[(size_t)e * Tn];  // trg[e, 0, 0]
  if (u == 0) out[(size_t)e * Tn] = xv;

  for (int t = 1; t < Tn; ++t) {
    v2f xx = v2f{xv, xv};
    v2f a01 = pkfma(xx, dw0i01, db0_01);
    v2f a23 = pkfma(xx, dw0i23, db0_23);
#pragma unroll
    for (int k = 0; k < 4; ++k) {
      v2f hh = v2f{h0g[k], h0g[k]};
      a01 = pkfma(hh, dw0h01[k], a01);
      a23 = pkfma(hh, dw0h23[k], a23);
    }
    float h0 = unit_update(a01, a23, c0);
    quad_gather(h0, h0g);

    v2f e01 = db1_01, e23 = db1_23;
#pragma unroll
    for (int k = 0; k < 4; ++k) {  // h1 part first
      v2f hh = v2f{h1g[k], h1g[k]};
      e01 = pkfma(hh, dw1h01[k], e01);
      e23 = pkfma(hh, dw1h23[k], e23);
    }
#pragma unroll
    for (int k = 0; k < 4; ++k) {  // h0 part last
      v2f hh = v2f{h0g[k], h0g[k]};
      e01 = pkfma(hh, dw1i01[k], e01);
      e23 = pkfma(hh, dw1i23[k], e23);
    }
    float h1 = unit_update(e01, e23, c1);
    quad_gather(h1, h1g);

    float pred = fcbv;
#pragma unroll
    for (int k = 0; k < 4; ++k) pred = fmaf(h1g[k], fcw[k], pred);
    // broadcast lane0's pred so all quad lanes stay bit-identical
    pred = qperm<DPP_BC0>(pred);
    if (u == 0) out[(size_t)e * Tn + t] = pred;
    xv = pred;
  }
}

}  // namespace

extern "C" void kernel_launch(void* const* d_in, const int* in_sizes, int n_in,
                              void* d_out, int out_size, void* d_ws, size_t ws_size,
                              hipStream_t stream) {
  const float* src = (const float*)d_in[0];
  const float* trg = (const float*)d_in[1];
  const float* eWih0 = (const float*)d_in[2];
  const float* eWhh0 = (const float*)d_in[3];
  const float* ebih0 = (const float*)d_in[4];
  const float* ebhh0 = (const float*)d_in[5];
  const float* eWih1 = (const float*)d_in[6];
  const float* eWhh1 = (const float*)d_in[7];
  const float* ebih1 = (const float*)d_in[8];
  const float* ebhh1 = (const float*)d_in[9];
  const float* dWih0 = (const float*)d_in[10];
  const float* dWhh0 = (const float*)d_in[11];
  const float* dbih0 = (const float*)d_in[12];
  const float* dbhh0 = (const float*)d_in[13];
  const float* dWih1 = (const float*)d_in[14];
  const float* dWhh1 = (const float*)d_in[15];
  const float* dbih1 = (const float*)d_in[16];
  const float* dbhh1 = (const float*)d_in[17];
  const float* fcW = (const float*)d_in[18];
  const float* fcb = (const float*)d_in[19];
  float* out = (float*)d_out;

  const int B = 32768;
  const int lanes = B * 4;          // 4 lanes per batch element
  const int block = 64;
  const int grid = lanes / block;   // 2048 blocks -> 8 waves/CU, 2/SIMD
  seq2seq_kernel<<<grid, block, 0, stream>>>(
      src, trg, eWih0, eWhh0, ebih0, ebhh0, eWih1, eWhh1, ebih1, ebhh1,
      dWih0, dWhh0, dbih0, dbhh0, dWih1, dWhh1, dbih1, dbhh1, fcW, fcb, out);
}

// Round 3
// 443.419 us; speedup vs baseline: 1.1661x; 1.1661x over previous
//
#include <hip/hip_runtime.h>

namespace {

constexpr int Sn = 256;   // encoder sequence length
constexpr int Tn = 12;    // decoder length
constexpr float L2E = 1.44269504088896340736f;  // log2(e)

typedef float v2f __attribute__((ext_vector_type(2)));

__device__ __forceinline__ v2f pkfma(v2f a, v2f b, v2f c) {
  return __builtin_elementwise_fma(a, b, c);  // -> v_pk_fma_f32 on gfx950
}

__device__ __forceinline__ float rcp_(float x) { return __builtin_amdgcn_rcpf(x); }

// Direct 2^x. Gate pre-activations are pre-scaled by +/-log2e at weight-load
// time, so activations need no runtime log2e multiply. (Validated in R2: same
// absmax as the __expf version.)
#if __has_builtin(__builtin_amdgcn_exp2f)
__device__ __forceinline__ float exp2_(float x) { return __builtin_amdgcn_exp2f(x); }
#else
__device__ __forceinline__ float exp2_(float x) { return __expf(x * 0.69314718055994530942f); }
#endif

// quad_perm DPP: lane i reads lane sel_i of its 4-lane quad. VALU-rate cross-lane.
template <int CTRL>
__device__ __forceinline__ float qperm(float v) {
  return __int_as_float(
      __builtin_amdgcn_mov_dpp(__float_as_int(v), CTRL, 0xF, 0xF, true));
}
constexpr int DPP_XOR1 = 0xB1;  // [1,0,3,2]
constexpr int DPP_XOR2 = 0x4E;  // [2,3,0,1]
constexpr int DPP_XOR3 = 0x1B;  // [3,2,1,0]
constexpr int DPP_BC0 = 0x00;   // [0,0,0,0]

// Pre-scaled gates: g01 = (-L2E*i, -L2E*f), g23 = (2*L2E*g, -L2E*o).
// Fused single-rcp forms (trans: 5 exp + 3 rcp, was 5+5):
//   i*g       = (eg-1) / ((1+ei)(eg+1))
//   f         = 1 / (1+ef)
//   o*tanh(c) = (ec-1) / ((1+eo)(ec+1)),  ec = 2^(2*L2E*c)
// The two tanh exponents are clamped at 64 (v_min_f32): beyond 2^26 the ratio
// rounds to 1.0f anyway, and the clamp closes the inf/inf -> NaN path. ei/ef/eo
// = inf are benign (denominator inf -> rcp 0 -> product with finite numerator).
__device__ __forceinline__ float unit_update(v2f g01, v2f g23, float& c) {
  float ei = exp2_(g01.x);
  float ef = exp2_(g01.y);
  float eg = exp2_(fminf(g23.x, 64.0f));
  float eo = exp2_(g23.y);
  float ig = (eg - 1.0f) * rcp_((1.0f + ei) * (eg + 1.0f));
  float fv = rcp_(1.0f + ef);
  c = fmaf(fv, c, ig);
  float ec = exp2_(fminf(c * (2.0f * L2E), 64.0f));
  return (ec - 1.0f) * rcp_((1.0f + eo) * (ec + 1.0f));
}

__device__ __forceinline__ void quad_gather(float h, float* hg) {
  hg[0] = h;
  hg[1] = qperm<DPP_XOR1>(h);
  hg[2] = qperm<DPP_XOR2>(h);
  hg[3] = qperm<DPP_XOR3>(h);
}

__global__ __launch_bounds__(64) void seq2seq_kernel(
    const float* __restrict__ src, const float* __restrict__ trg,
    const float* __restrict__ eWih0, const float* __restrict__ eWhh0,
    const float* __restrict__ ebih0, const float* __restrict__ ebhh0,
    const float* __restrict__ eWih1, const float* __restrict__ eWhh1,
    const float* __restrict__ ebih1, const float* __restrict__ ebhh1,
    const float* __restrict__ dWih0, const float* __restrict__ dWhh0,
    const float* __restrict__ dbih0, const float* __restrict__ dbhh0,
    const float* __restrict__ dWih1, const float* __restrict__ dWhh1,
    const float* __restrict__ dbih1, const float* __restrict__ dbhh1,
    const float* __restrict__ fcW, const float* __restrict__ fcb,
    float* __restrict__ out) {
  const int gid = blockIdx.x * 64 + threadIdx.x;
  const int e = gid >> 2;  // batch element
  const int u = gid & 3;   // hidden unit owned by this lane

  // Gate rows for this lane: i=u, f=4+u, g=8+u, o=12+u.
  const int ri = u, rf = 4 + u, rg = 8 + u, ro = 12 + u;

  // Activation scale folded into weights: (i,f,o) get -L2E (sigmoid), g gets
  // +2*L2E (tanh).
  const v2f s01 = v2f{-L2E, -L2E};
  const v2f s23 = v2f{2.0f * L2E, -L2E};

  v2f w0x01[8], w0x23[8], w0h01[4], w0h23[4];
  v2f w1i01[4], w1i23[4], w1h01[4], w1h23[4];
#pragma unroll
  for (int j = 0; j < 8; ++j) {
    w0x01[j] = v2f{eWih0[ri * 8 + j], eWih0[rf * 8 + j]} * s01;
    w0x23[j] = v2f{eWih0[rg * 8 + j], eWih0[ro * 8 + j]} * s23;
  }
#pragma unroll
  for (int k = 0; k < 4; ++k) {
    const int kc = u ^ k;
    w0h01[k] = v2f{eWhh0[ri * 4 + kc], eWhh0[rf * 4 + kc]} * s01;
    w0h23[k] = v2f{eWhh0[rg * 4 + kc], eWhh0[ro * 4 + kc]} * s23;
    w1i01[k] = v2f{eWih1[ri * 4 + kc], eWih1[rf * 4 + kc]} * s01;
    w1i23[k] = v2f{eWih1[rg * 4 + kc], eWih1[ro * 4 + kc]} * s23;
    w1h01[k] = v2f{eWhh1[ri * 4 + kc], eWhh1[rf * 4 + kc]} * s01;
    w1h23[k] = v2f{eWhh1[rg * 4 + kc], eWhh1[ro * 4 + kc]} * s23;
  }
  const v2f b0_01 = v2f{ebih0[ri] + ebhh0[ri], ebih0[rf] + ebhh0[rf]} * s01;
  const v2f b0_23 = v2f{ebih0[rg] + ebhh0[rg], ebih0[ro] + ebhh0[ro]} * s23;
  const v2f b1_01 = v2f{ebih1[ri] + ebhh1[ri], ebih1[rf] + ebhh1[rf]} * s01;
  const v2f b1_23 = v2f{ebih1[rg] + ebhh1[rg], ebih1[ro] + ebhh1[ro]} * s23;

  const float4* sp = (const float4*)(src + (size_t)e * (Sn * 8));

  float h0g[4] = {0, 0, 0, 0};  // h0g[k] = h0[u^k]
  float h1g[4] = {0, 0, 0, 0};
  float c0 = 0.0f, c1 = 0.0f;

  // One full LSTM step (both layers) given this step's 8 inputs.
  // L0: x-part (16 pkfma, off the recurrent chain) heads the accumulator
  // chain, h-part (4 deps) is the tail. L1: h1-part first, h0-part last, so
  // only 4 pkfma sit on the critical path after h0 resolves.
  auto enc_step = [&](float4 xa, float4 xb) {
    float x[8] = {xa.x, xa.y, xa.z, xa.w, xb.x, xb.y, xb.z, xb.w};
    v2f a01 = b0_01, a23 = b0_23;
#pragma unroll
    for (int j = 0; j < 8; ++j) {
      v2f xx = v2f{x[j], x[j]};
      a01 = pkfma(xx, w0x01[j], a01);
      a23 = pkfma(xx, w0x23[j], a23);
    }
#pragma unroll
    for (int k = 0; k < 4; ++k) {
      v2f hh = v2f{h0g[k], h0g[k]};
      a01 = pkfma(hh, w0h01[k], a01);
      a23 = pkfma(hh, w0h23[k], a23);
    }
    float h0 = unit_update(a01, a23, c0);
    quad_gather(h0, h0g);

    v2f e01 = b1_01, e23 = b1_23;
#pragma unroll
    for (int k = 0; k < 4; ++k) {  // h1 part first (independent of h0)
      v2f hh = v2f{h1g[k], h1g[k]};
      e01 = pkfma(hh, w1h01[k], e01);
      e23 = pkfma(hh, w1h23[k], e23);
    }
#pragma unroll
    for (int k = 0; k < 4; ++k) {  // h0 part last (short tail on critical path)
      v2f hh = v2f{h0g[k], h0g[k]};
      e01 = pkfma(hh, w1i01[k], e01);
      e23 = pkfma(hh, w1i23[k], e23);
    }
    float h1 = unit_update(e01, e23, c1);
    quad_gather(h1, h1g);
  };

  // ---------------- encoder: 256 steps ----------------
  // R1's proven double-buffered register FIFO (8 steps / 16 float4 per
  // buffer), unchanged: 140 VGPR, no spill. (R2's 3-buffer variant spilled:
  // WRITE_SIZE 1.5MB -> 412MB. Do not enlarge the live set.)
  float4 A[16], B[16];
#pragma unroll
  for (int j = 0; j < 16; ++j) A[j] = sp[j];        // steps 0..7
#pragma unroll
  for (int j = 0; j < 16; ++j) B[j] = sp[16 + j];   // steps 8..15

  for (int i = 0; i < 16; ++i) {  // 16 outer iters x 16 steps = 256
#pragma unroll
    for (int s = 0; s < 8; ++s) enc_step(A[2 * s], A[2 * s + 1]);
    if (i < 15) {  // refill A with steps 16(i+1)..16(i+1)+7
#pragma unroll
      for (int j = 0; j < 16; ++j) A[j] = sp[32 * (i + 1) + j];
    }
#pragma unroll
    for (int s = 0; s < 8; ++s) enc_step(B[2 * s], B[2 * s + 1]);
    if (i < 15) {  // refill B with steps 16(i+1)+8..16(i+1)+15
#pragma unroll
      for (int j = 0; j < 16; ++j) B[j] = sp[32 * (i + 1) + 16 + j];
    }
  }

  // ---- decoder weights (loaded after encoder; encoder weights now dead) ----
  v2f dw0i01 = v2f{dWih0[ri], dWih0[rf]} * s01;
  v2f dw0i23 = v2f{dWih0[rg], dWih0[ro]} * s23;
  v2f dw0h01[4], dw0h23[4], dw1i01[4], dw1i23[4], dw1h01[4], dw1h23[4];
#pragma unroll
  for (int k = 0; k < 4; ++k) {
    const int kc = u ^ k;
    dw0h01[k] = v2f{dWhh0[ri * 4 + kc], dWhh0[rf * 4 + kc]} * s01;
    dw0h23[k] = v2f{dWhh0[rg * 4 + kc], dWhh0[ro * 4 + kc]} * s23;
    dw1i01[k] = v2f{dWih1[ri * 4 + kc], dWih1[rf * 4 + kc]} * s01;
    dw1i23[k] = v2f{dWih1[rg * 4 + kc], dWih1[ro * 4 + kc]} * s23;
    dw1h01[k] = v2f{dWhh1[ri * 4 + kc], dWhh1[rf * 4 + kc]} * s01;
    dw1h23[k] = v2f{dWhh1[rg * 4 + kc], dWhh1[ro * 4 + kc]} * s23;
  }
  const v2f db0_01 = v2f{dbih0[ri] + dbhh0[ri], dbih0[rf] + dbhh0[rf]} * s01;
  const v2f db0_23 = v2f{dbih0[rg] + dbhh0[rg], dbih0[ro] + dbhh0[ro]} * s23;
  const v2f db1_01 = v2f{dbih1[ri] + dbhh1[ri], dbih1[rf] + dbhh1[rf]} * s01;
  const v2f db1_23 = v2f{dbih1[rg] + dbhh1[rg], dbih1[ro] + dbhh1[ro]} * s23;
  float fcw[4];
#pragma unroll
  for (int k = 0; k < 4; ++k) fcw[k] = fcW[u ^ k];
  const float fcbv = fcb[0];

  // ---------------- decoder: 11 steps ----------------
  float xv = trg[(size_t)e * Tn];  // trg[e, 0, 0]
  if (u == 0) out[(size_t)e * Tn] = xv;

  for (int t = 1; t < Tn; ++t) {
    v2f xx = v2f{xv, xv};
    v2f a01 = pkfma(xx, dw0i01, db0_01);
    v2f a23 = pkfma(xx, dw0i23, db0_23);
#pragma unroll
    for (int k = 0; k < 4; ++k) {
      v2f hh = v2f{h0g[k], h0g[k]};
      a01 = pkfma(hh, dw0h01[k], a01);
      a23 = pkfma(hh, dw0h23[k], a23);
    }
    float h0 = unit_update(a01, a23, c0);
    quad_gather(h0, h0g);

    v2f e01 = db1_01, e23 = db1_23;
#pragma unroll
    for (int k = 0; k < 4; ++k) {  // h1 part first
      v2f hh = v2f{h1g[k], h1g[k]};
      e01 = pkfma(hh, dw1h01[k], e01);
      e23 = pkfma(hh, dw1h23[k], e23);
    }
#pragma unroll
    for (int k = 0; k < 4; ++k) {  // h0 part last
      v2f hh = v2f{h0g[k], h0g[k]};
      e01 = pkfma(hh, dw1i01[k], e01);
      e23 = pkfma(hh, dw1i23[k], e23);
    }
    float h1 = unit_update(e01, e23, c1);
    quad_gather(h1, h1g);

    float pred = fcbv;
#pragma unroll
    for (int k = 0; k < 4; ++k) pred = fmaf(h1g[k], fcw[k], pred);
    // broadcast lane0's pred so all quad lanes stay bit-identical
    pred = qperm<DPP_BC0>(pred);
    if (u == 0) out[(size_t)e * Tn + t] = pred;
    xv = pred;
  }
}

}  // namespace

extern "C" void kernel_launch(void* const* d_in, const int* in_sizes, int n_in,
                              void* d_out, int out_size, void* d_ws, size_t ws_size,
                              hipStream_t stream) {
  const float* src = (const float*)d_in[0];
  const float* trg = (const float*)d_in[1];
  const float* eWih0 = (const float*)d_in[2];
  const float* eWhh0 = (const float*)d_in[3];
  const float* ebih0 = (const float*)d_in[4];
  const float* ebhh0 = (const float*)d_in[5];
  const float* eWih1 = (const float*)d_in[6];
  const float* eWhh1 = (const float*)d_in[7];
  const float* ebih1 = (const float*)d_in[8];
  const float* ebhh1 = (const float*)d_in[9];
  const float* dWih0 = (const float*)d_in[10];
  const float* dWhh0 = (const float*)d_in[11];
  const float* dbih0 = (const float*)d_in[12];
  const float* dbhh0 = (const float*)d_in[13];
  const float* dWih1 = (const float*)d_in[14];
  const float* dWhh1 = (const float*)d_in[15];
  const float* dbih1 = (const float*)d_in[16];
  const float* dbhh1 = (const float*)d_in[17];
  const float* fcW = (const float*)d_in[18];
  const float* fcb = (const float*)d_in[19];
  float* out = (float*)d_out;

  const int B = 32768;
  const int lanes = B * 4;          // 4 lanes per batch element
  const int block = 64;
  const int grid = lanes / block;   // 2048 blocks -> 8 waves/CU, 2/SIMD
  seq2seq_kernel<<<grid, block, 0, stream>>>(
      src, trg, eWih0, eWhh0, ebih0, ebhh0, eWih1, eWhh1, ebih1, ebhh1,
      dWih0, dWhh0, dbih0, dbhh0, dWih1, dWhh1, dbih1, dbhh1, fcW, fcb, out);
}